// Round 7
// baseline (455.179 us; speedup 1.0000x reference)
//
#include <hip/hip_runtime.h>

// LSTM B=4096 T=336 I=21 H=50 OUT=24, fp32 in/out.
// Round 7: latency-overlap structure. 512 wgs x 448 thr (7 waves), MB=8
// batches/wg -> 2 independent wgs per CU (independent barriers overlap each
// other's serial chains). Wave w owns M-tiles {2w, 2w+1} (tile 13 = pad).
// Numerics (from R6): activations single fp16 limb in LDS, weights 2 fp16
// limbs in VGPRs; gates = Wh.B + Wl.B (err ~2^-11 act, 2^-22 weights).
// x global prefetch at distance 2 iterations -> no exposed vmem latency.
// Conflict-free LDS layout [buf][kblock][col16][8] (cols 8..15 zero-pad):
//   kblock 0..7 = h (k 0..63), kblock 8..11 = x (k 64..95).
// B-frag read = const + lane*16B. Packed gate row = unit*4+gate -> lane's
// 4 acc regs = 4 gates of one unit; pointwise fully in registers.

#define T_SEQ 336
#define I_IN  21
#define HID   50
#define O_OUT 24
#define MB    8
#define NT    448
#define NTILE 13
#define KB    12

#define AIDX(buf, kb, n, j) ((((buf)*KB + (kb))*16 + (n))*8 + (j))

typedef _Float16 f16x8 __attribute__((ext_vector_type(8)));
typedef float    f32x4 __attribute__((ext_vector_type(4)));

static __device__ __forceinline__ float frcp(float v) { return __builtin_amdgcn_rcpf(v); }
static __device__ __forceinline__ float sigm(float v) { return frcp(1.f + __expf(-v)); }
// tanh(v) = 1 - 2/(1+e^{2v}); overflow -> inf -> rcp -> 0 -> +1 (correct)
static __device__ __forceinline__ float tanh_f(float v) {
    return __builtin_fmaf(-2.f, frcp(1.f + __expf(2.f * v)), 1.f);
}

__global__ __launch_bounds__(NT)
void lstm_mfma7(const float* __restrict__ x,
                const float* __restrict__ W_ih,
                const float* __restrict__ W_hh,
                const float* __restrict__ b_ih,
                const float* __restrict__ b_hh,
                const float* __restrict__ W_fc,
                const float* __restrict__ b_fc,
                float* __restrict__ out)
{
    __shared__ _Float16 sAct[2 * KB * 16 * 8];   // 3072 halves = 6 KB

    const int tid  = threadIdx.x;
    const int lane = tid & 63;
    const int wv   = tid >> 6;        // 0..6
    const int nl   = lane & 15;       // A: row-in-tile / B: batch col (0..7 valid)
    const int q    = lane >> 4;       // quad
    const int b0   = blockIdx.x * MB;

    // ---- zero-init LDS (pad cols/rows must stay 0 forever; h(0)=0) ----
    for (int i = tid; i < 2 * KB * 16 * 8; i += NT) sAct[i] = (_Float16)0.f;

    // ---- A (weight) 2-limb fp16 fragments + bias for 2 tiles, built once ----
    const bool t1ok = (2 * wv + 1) < NTILE;     // wave 6's 2nd tile is pad
    f16x8 Wh[2][3], Wl[2][3];
    f32x4 biasv[2];
    #pragma unroll
    for (int tt = 0; tt < 2; ++tt) {
        const int tile = 2 * wv + tt;
        const int p    = tile * 16 + nl;         // packed row
        const int unit = p >> 2, gate = p & 3;
        const bool vr  = (unit < HID) && (tile < NTILE);
        const int orig = gate * HID + unit;      // i,f,g,o stacked row
        const int ub   = tile * 4 + q;           // unit for D rows q*4+r
        #pragma unroll
        for (int r = 0; r < 4; ++r)
            biasv[tt][r] = (ub < HID) ? (b_ih[r * HID + ub] + b_hh[r * HID + ub]) : 0.f;
        #pragma unroll
        for (int kc = 0; kc < 3; ++kc) {
            #pragma unroll
            for (int j = 0; j < 8; ++j) {
                const int k = kc * 32 + q * 8 + j;
                float w = 0.f;
                if (vr) {
                    if (k < 64) { if (k < HID) w = W_hh[orig * HID + k]; }
                    else { const int ki = k - 64; if (ki < I_IN) w = W_ih[orig * I_IN + ki]; }
                }
                const _Float16 hi = (_Float16)w;
                Wh[tt][kc][j] = hi;
                Wl[tt][kc][j] = (_Float16)(w - (float)hi);
            }
        }
    }

    __syncthreads();   // zero-init complete before x(0) staging

    // ---- x staging role: threads 0..167, one (b,i) each ----
    const bool stg = tid < MB * I_IN;            // 168
    const int  sb  = stg ? tid / I_IN : 0;
    const int  sk  = stg ? tid % I_IN : 0;
    const float* xg = x + (size_t)(b0 + sb) * T_SEQ * I_IN + sk;
    const int  xoff = AIDX(0, 8 + (sk >> 3), sb, sk & 7);   // + buf*BUFS
    const int  BUFS = KB * 16 * 8;
    if (stg) sAct[xoff] = (_Float16)xg[0];

    // prefetch pipeline, distance 2: pfA -> commit at t (x(t+1)), pfB spare
    float pfA = 0.f, pfB = 0.f;
    if (stg) {
        pfA = xg[(size_t)1 * I_IN];              // x(1)
        pfB = xg[(size_t)2 * I_IN];              // x(2)
    }

    // pointwise: lane owns units 8wv+q (tt=0), 8wv+4+q (tt=1) for batch nl
    const int  uown[2] = {8 * wv + q, 8 * wv + 4 + q};
    const bool uval[2] = {uown[0] < HID && nl < MB,
                          uown[1] < HID && nl < MB && t1ok};
    const int  hoff[2] = {AIDX(0, uown[0] >> 3, nl, uown[0] & 7),
                          AIDX(0, uown[1] >> 3, nl, uown[1] & 7)};
    float cst[2] = {0.f, 0.f};

    const _Float16* bb0 = &sAct[AIDX(0, q, nl, 0)];
    const _Float16* bb1 = &sAct[AIDX(1, q, nl, 0)];

    for (int t = 0; t < T_SEQ; ++t) {
        const int nxt = (t & 1) ^ 1;

        __syncthreads();   // sAct[cur] (h(t) + x(t)) complete

        // ---- B (activation) fragments: 3 contiguous b128 reads ----
        const _Float16* bb = (t & 1) ? bb1 : bb0;
        const f16x8 B0 = *(const f16x8*)(bb);
        const f16x8 B1 = *(const f16x8*)(bb + 4 * 16 * 8);
        const f16x8 B2 = *(const f16x8*)(bb + 8 * 16 * 8);

        // commit x(t+1) (loaded 2 iterations ago -> no exposed latency)
        if (stg && (t + 1 < T_SEQ)) sAct[nxt * BUFS + xoff] = (_Float16)pfA;
        // issue load of x(t+3)
        float pfN = 0.f;
        if (stg && (t + 3 < T_SEQ)) pfN = xg[(size_t)(t + 3) * I_IN];

        // ---- MFMA: 4 independent chains (hi/lo limb x 2 tiles) ----
        f32x4 aA0 = biasv[0], aB0 = {0.f, 0.f, 0.f, 0.f};
        f32x4 aA1 = biasv[1], aB1 = {0.f, 0.f, 0.f, 0.f};
        aA0 = __builtin_amdgcn_mfma_f32_16x16x32_f16(Wh[0][0], B0, aA0, 0, 0, 0);
        aB0 = __builtin_amdgcn_mfma_f32_16x16x32_f16(Wl[0][0], B0, aB0, 0, 0, 0);
        if (t1ok) {
            aA1 = __builtin_amdgcn_mfma_f32_16x16x32_f16(Wh[1][0], B0, aA1, 0, 0, 0);
            aB1 = __builtin_amdgcn_mfma_f32_16x16x32_f16(Wl[1][0], B0, aB1, 0, 0, 0);
        }
        aA0 = __builtin_amdgcn_mfma_f32_16x16x32_f16(Wh[0][1], B1, aA0, 0, 0, 0);
        aB0 = __builtin_amdgcn_mfma_f32_16x16x32_f16(Wl[0][1], B1, aB0, 0, 0, 0);
        if (t1ok) {
            aA1 = __builtin_amdgcn_mfma_f32_16x16x32_f16(Wh[1][1], B1, aA1, 0, 0, 0);
            aB1 = __builtin_amdgcn_mfma_f32_16x16x32_f16(Wl[1][1], B1, aB1, 0, 0, 0);
        }
        aA0 = __builtin_amdgcn_mfma_f32_16x16x32_f16(Wh[0][2], B2, aA0, 0, 0, 0);
        aB0 = __builtin_amdgcn_mfma_f32_16x16x32_f16(Wl[0][2], B2, aB0, 0, 0, 0);
        if (t1ok) {
            aA1 = __builtin_amdgcn_mfma_f32_16x16x32_f16(Wh[1][2], B2, aA1, 0, 0, 0);
            aB1 = __builtin_amdgcn_mfma_f32_16x16x32_f16(Wl[1][2], B2, aB1, 0, 0, 0);
        }

        // ---- pointwise cell update, fully in registers ----
        #pragma unroll
        for (int tt = 0; tt < 2; ++tt) {
            if (uval[tt]) {
                const f32x4 aA = (tt == 0) ? aA0 : aA1;
                const f32x4 aB = (tt == 0) ? aB0 : aB1;
                const float gi = aA[0] + aB[0];
                const float gf = aA[1] + aB[1];
                const float gg = aA[2] + aB[2];
                const float go = aA[3] + aB[3];
                float c = cst[tt];
                c = __builtin_fmaf(sigm(gf), c, sigm(gi) * tanh_f(gg));
                cst[tt] = c;
                const float h = sigm(go) * tanh_f(c);
                sAct[nxt * BUFS + hoff[tt]] = (_Float16)h;
            }
        }

        // rotate prefetch pipeline
        pfA = pfB;
        pfB = pfN;
    }

    __syncthreads();
    // final h: t=335 wrote buf 0
    // ---- FC epilogue: 8*24 = 192 tasks (one-time) ----
    if (tid < MB * O_OUT) {
        const int b = tid / O_OUT, o = tid % O_OUT;
        float a = b_fc[o];
        for (int u = 0; u < HID; ++u) {
            const float hv = (float)sAct[AIDX(0, u >> 3, b, u & 7)];
            a = __builtin_fmaf(hv, W_fc[o * HID + u], a);
        }
        out[(size_t)(b0 + b) * O_OUT + o] = a;
    }
}

extern "C" void kernel_launch(void* const* d_in, const int* in_sizes, int n_in,
                              void* d_out, int out_size, void* d_ws, size_t ws_size,
                              hipStream_t stream)
{
    const float* x    = (const float*)d_in[0];
    const float* W_ih = (const float*)d_in[1];
    const float* W_hh = (const float*)d_in[2];
    const float* b_ih = (const float*)d_in[3];
    const float* b_hh = (const float*)d_in[4];
    const float* W_fc = (const float*)d_in[5];
    const float* b_fc = (const float*)d_in[6];
    float* out = (float*)d_out;

    lstm_mfma7<<<dim3(4096 / MB), dim3(NT), 0, stream>>>(
        x, W_ih, W_hh, b_ih, b_hh, W_fc, b_fc, out);
}

// Round 8
// 325.628 us; speedup vs baseline: 1.3979x; 1.3979x over previous
//
#include <hip/hip_runtime.h>

// LSTM B=4096 T=336 I=21 H=50 OUT=24, fp32 in/out.
// Round 8: chunked x-staging to remove ALL global loads (and their
// vmcnt(0)-before-s_barrier drains) from the steady-state step loop.
//   - 256 wgs x 832 thr = 13 waves, one 16-row M-tile per wave (R4 shape).
//   - Numerics (R6): activations single fp16 in LDS; weights 2 fp16 limbs in
//     VGPRs; gates = Wh.B + Wl.B. 6 MFMA + 3 ds_read_b128 per wave per step.
//   - x staged per chunk of CH=12 steps into double-buffered LDS in MFMA
//     B-layout. Global loads only on step 0 of each chunk, issued right
//     after the barrier (max slack); steps 1..11 have no outstanding vmem.
// LDS layouts (halves), all conflict-free (B-frag read = const + lane*16B):
//   hbuf[buf2][kb8][col16][8]   : h, k=0..63 (units 0..49 valid, rest 0)
//   xC[buf2][s12][kb4][col16][8]: x, k=64..95 (i=k-64 < 21 valid, rest 0)
// Packed gate row = unit*4 + gate -> lane's 4 acc regs = 4 gates of one
// unit; pointwise LSTM update fully in registers.

#define T_SEQ 336
#define I_IN  21
#define HID   50
#define O_OUT 24
#define MB    16
#define NT    832
#define NTILE 13
#define CH    12
#define NCH   28                     // 336 / 12
#define XELEM (CH * MB * I_IN)       // 4032 floats per chunk
#define NLD   5                      // ceil(4032 / 832)
#define XBUFH (CH * 4 * 16 * 8)      // 6144 halves per x chunk buffer

#define HIDX(buf, kb, n, j) ((((buf)*8 + (kb))*16 + (n))*8 + (j))
#define XIDX(s, kb, n, j)   ((((s)*4 + (kb))*16 + (n))*8 + (j))

typedef _Float16 f16x8 __attribute__((ext_vector_type(8)));
typedef float    f32x4 __attribute__((ext_vector_type(4)));

static __device__ __forceinline__ float frcp(float v) { return __builtin_amdgcn_rcpf(v); }
static __device__ __forceinline__ float sigm(float v) { return frcp(1.f + __expf(-v)); }
// tanh(v) = 1 - 2/(1+e^{2v}); overflow -> inf -> rcp -> 0 -> +1 (correct)
static __device__ __forceinline__ float tanh_f(float v) {
    return __builtin_fmaf(-2.f, frcp(1.f + __expf(2.f * v)), 1.f);
}

__global__ __launch_bounds__(NT)
void lstm_mfma8(const float* __restrict__ x,
                const float* __restrict__ W_ih,
                const float* __restrict__ W_hh,
                const float* __restrict__ b_ih,
                const float* __restrict__ b_hh,
                const float* __restrict__ W_fc,
                const float* __restrict__ b_fc,
                float* __restrict__ out)
{
    __shared__ _Float16 hbuf[2 * 8 * 16 * 8];   // 2048 halves = 4 KB
    __shared__ _Float16 xC[2 * XBUFH];          // 12288 halves = 24 KB

    const int tid  = threadIdx.x;
    const int lane = tid & 63;
    const int wv   = tid >> 6;        // 0..12 == M-tile
    const int nl   = lane & 15;       // A: row-in-tile / B: batch col
    const int q    = lane >> 4;       // quad
    const int b0   = blockIdx.x * MB;

    // ---- zero-init LDS (pads must stay 0 forever; h(0)=0) ----
    for (int i = tid; i < 2 * 8 * 16 * 8; i += NT) hbuf[i] = (_Float16)0.f;
    for (int i = tid; i < 2 * XBUFH;      i += NT) xC[i]   = (_Float16)0.f;

    // ---- x staging precompute + issue chunk-0 loads (drained at barrier) ----
    // element e = tid + k*NT of a chunk: e = ((sI*16)+b)*21 + i
    const float* px[NLD];
    int  xdst[NLD];
    bool xv[NLD];
    float sv[NLD];
    #pragma unroll
    for (int k = 0; k < NLD; ++k) {
        const int e  = tid + k * NT;
        const int i  = e % I_IN;
        const int r  = e / I_IN;
        const int b  = r & 15;
        const int sI = r >> 4;
        xv[k]   = (e < XELEM);
        px[k]   = x + ((size_t)(b0 + b) * T_SEQ + sI) * I_IN + i;
        xdst[k] = XIDX(sI, i >> 3, b, i & 7);
        sv[k]   = px[k][0];            // chunk 0 (loads overlap weight build)
    }

    // ---- A (weight) 2-limb fp16 fragments + bias, built once ----
    // A[m=nl][k = kc*32 + q*8 + j]; packed row p = wv*16+nl -> unit=p>>2, gate=p&3
    f16x8 Wh[3], Wl[3];
    f32x4 biasv;
    {
        const int p    = wv * 16 + nl;
        const int unit = p >> 2, gate = p & 3;
        const bool vr  = (unit < HID);
        const int orig = gate * HID + unit;       // i,f,g,o stacked row
        const int ub   = wv * 4 + q;              // unit for D rows q*4+r
        #pragma unroll
        for (int r = 0; r < 4; ++r)
            biasv[r] = (ub < HID) ? (b_ih[r * HID + ub] + b_hh[r * HID + ub]) : 0.f;
        #pragma unroll
        for (int kc = 0; kc < 3; ++kc) {
            #pragma unroll
            for (int j = 0; j < 8; ++j) {
                const int k = kc * 32 + q * 8 + j;
                float w = 0.f;
                if (vr) {
                    if (k < 64) { if (k < HID) w = W_hh[orig * HID + k]; }
                    else { const int ki = k - 64; if (ki < I_IN) w = W_ih[orig * I_IN + ki]; }
                }
                const _Float16 hi = (_Float16)w;
                Wh[kc][j] = hi;
                Wl[kc][j] = (_Float16)(w - (float)hi);
            }
        }
    }

    __syncthreads();   // zero-init visible (chunk-0 loads drained here too)

    // ---- commit chunk 0 into xC buf 0; advance pointers to chunk 1 ----
    #pragma unroll
    for (int k = 0; k < NLD; ++k) {
        if (xv[k]) xC[xdst[k]] = (_Float16)sv[k];
        px[k] += CH * I_IN;
    }

    // pointwise: lane owns unit uown = 4wv+q for batch nl (c in register)
    const int  uown = wv * 4 + q;
    const bool uval = (uown < HID);
    const int  hwo  = ((uown >> 3) * 16 + nl) * 8 + (uown & 7);  // + buf*1024
    float cst = 0.f;

    const _Float16* hb0 = &hbuf[HIDX(0, q, nl, 0)];
    const int bfo = ((q * 16) + nl) * 8;           // x B-frag offset within step

    for (int c = 0; c < NCH; ++c) {
        const int  rb    = (c & 1) * XBUFH;
        const int  wb    = ((c + 1) & 1) * XBUFH;
        const bool dostg = (c + 1) < NCH;
        #pragma unroll 2
        for (int s = 0; s < CH; ++s) {
            __syncthreads();   // hbuf[cur] (h) complete; xC[rb] chunk staged

            // staging loads for next chunk: first thing after the barrier
            // (max slack before this step's closing drain)
            if (s == 0 && dostg) {
                #pragma unroll
                for (int k = 0; k < NLD; ++k) sv[k] = px[k][0];
            }

            const int cur = s & 1, nxt = cur ^ 1;

            // ---- B (activation) fragments: 3 contiguous b128 reads ----
            const _Float16* hb = hb0 + cur * 1024;
            const f16x8 B0 = *(const f16x8*)(hb);
            const f16x8 B1 = *(const f16x8*)(hb + 4 * 16 * 8);
            const f16x8 B2 = *(const f16x8*)&xC[rb + s * 512 + bfo];

            // ---- MFMA: two independent 3-deep chains (hi/lo weight limb) ----
            f32x4 aA = biasv;
            f32x4 aB = {0.f, 0.f, 0.f, 0.f};
            aA = __builtin_amdgcn_mfma_f32_16x16x32_f16(Wh[0], B0, aA, 0, 0, 0);
            aB = __builtin_amdgcn_mfma_f32_16x16x32_f16(Wl[0], B0, aB, 0, 0, 0);
            aA = __builtin_amdgcn_mfma_f32_16x16x32_f16(Wh[1], B1, aA, 0, 0, 0);
            aB = __builtin_amdgcn_mfma_f32_16x16x32_f16(Wl[1], B1, aB, 0, 0, 0);
            aA = __builtin_amdgcn_mfma_f32_16x16x32_f16(Wh[2], B2, aA, 0, 0, 0);
            aB = __builtin_amdgcn_mfma_f32_16x16x32_f16(Wl[2], B2, aB, 0, 0, 0);

            // ---- pointwise cell update, fully in registers ----
            if (uval) {
                const float gi = aA[0] + aB[0];
                const float gf = aA[1] + aB[1];
                const float gg = aA[2] + aB[2];
                const float go = aA[3] + aB[3];
                float cc = cst;
                cc = __builtin_fmaf(sigm(gf), cc, sigm(gi) * tanh_f(gg));
                cst = cc;
                const float h = sigm(go) * tanh_f(cc);
                hbuf[nxt * 1024 + hwo] = (_Float16)h;
            }

            // ---- commit staged x(next chunk) into the other x buffer ----
            if (s == 0 && dostg) {
                #pragma unroll
                for (int k = 0; k < NLD; ++k) {
                    if (xv[k]) xC[wb + xdst[k]] = (_Float16)sv[k];
                    px[k] += CH * I_IN;
                }
            }
        }
    }

    __syncthreads();
    // final h: t=335 wrote buf 0
    // ---- FC epilogue: 16*24 = 384 tasks (one-time) ----
    if (tid < MB * O_OUT) {
        const int b = tid / O_OUT, o = tid % O_OUT;
        float a = b_fc[o];
        for (int u = 0; u < HID; ++u) {
            const float hv = (float)hbuf[HIDX(0, u >> 3, b, u & 7)];
            a = __builtin_fmaf(hv, W_fc[o * HID + u], a);
        }
        out[(size_t)(b0 + b) * O_OUT + o] = a;
    }
}

extern "C" void kernel_launch(void* const* d_in, const int* in_sizes, int n_in,
                              void* d_out, int out_size, void* d_ws, size_t ws_size,
                              hipStream_t stream)
{
    const float* x    = (const float*)d_in[0];
    const float* W_ih = (const float*)d_in[1];
    const float* W_hh = (const float*)d_in[2];
    const float* b_ih = (const float*)d_in[3];
    const float* b_hh = (const float*)d_in[4];
    const float* W_fc = (const float*)d_in[5];
    const float* b_fc = (const float*)d_in[6];
    float* out = (float*)d_out;

    lstm_mfma8<<<dim3(4096 / MB), dim3(NT), 0, stream>>>(
        x, W_ih, W_hh, b_ih, b_hh, W_fc, b_fc, out);
}